// Round 5
// baseline (703.398 us; speedup 1.0000x reference)
//
#include <hip/hip_runtime.h>

typedef _Float16 f16;
typedef __attribute__((ext_vector_type(8))) _Float16 half8;
typedef __attribute__((ext_vector_type(2))) _Float16 half2v;
typedef __attribute__((ext_vector_type(4))) float float4v;

#define NNODES 50000
#define NEDGES 800000
#define NREL 8
#define NRSEG (NNODES * NREL)   // 400000 segments (dst, rel)
#define KDIM 1152               // (R+1)*128
#define CAP 24                  // bucket capacity per segment (Poisson(2) max << 24)
#define CAPQ (CAP / 4)

// one kernel builds the whole edge structure: count + bucket scatter
__global__ void bucket_fill(const int* __restrict__ src, const int* __restrict__ dst,
                            const int* __restrict__ et, int* __restrict__ cnt,
                            int* __restrict__ esrc) {
    int e = blockIdx.x * blockDim.x + threadIdx.x;
    if (e < NEDGES) {
        int s = dst[e] * NREL + et[e];
        int p = atomicAdd(&cnt[s], 1);
        if (p < CAP) esrc[s * CAP + p] = src[e];
    }
}

// fp32 [N,128] -> fp16 [N,128]
__global__ void cvt_x(const float* __restrict__ x, f16* __restrict__ x16) {
    int t = blockIdx.x * blockDim.x + threadIdx.x;
    if (t >= NNODES * 64) return;
    float2 v = ((const float2*)x)[t];
    half2v o = {(f16)v.x, (f16)v.y};
    ((half2v*)x16)[t] = o;
}

// all 3 layers' weights -> fp16 Bt[h][k] concatenated: rows 0..127 L1, 128..255 L2, 256..319 L3
__global__ void prep_w_all(const float* __restrict__ W1, const float* __restrict__ Wr1,
                           const float* __restrict__ W2, const float* __restrict__ Wr2,
                           const float* __restrict__ W3, const float* __restrict__ Wr3,
                           f16* __restrict__ Bt) {
    int idx = blockIdx.x * blockDim.x + threadIdx.x;
    if (idx >= 320 * KDIM) return;
    int hg = idx / KDIM, k = idx - hg * KDIM;
    const float *W, *Wr;
    int h, H;
    if (hg < 128)      { W = W1; Wr = Wr1; h = hg;       H = 128; }
    else if (hg < 256) { W = W2; Wr = Wr2; h = hg - 128; H = 128; }
    else               { W = W3; Wr = Wr3; h = hg - 256; H = 64;  }
    float v = (k < 1024) ? W[(size_t)k * H + h] : Wr[(size_t)(k - 1024) * H + h];
    Bt[idx] = (f16)v;
}

// Fused RGCN layer. Per 128-node tile: for r=0..7 build the segment-mean tile in LDS
// (XOR-swizzled 16B granules) and MFMA against global-resident Bt; root slot (r=8)
// MFMAs directly from act (no LDS). MODE 0: bias+BN+ReLU -> fp16. MODE 1: bias+sigmoid -> fp32.
template <int H, int MODE>
__global__ __launch_bounds__(256, 4) void fused_layer(
    const f16* __restrict__ act, const f16* __restrict__ Bt,
    const int* __restrict__ cnt, const int* __restrict__ esrc,
    const float* __restrict__ bias, const float* __restrict__ g,
    const float* __restrict__ be, const float* __restrict__ rm,
    const float* __restrict__ rv, f16* __restrict__ hout, float* __restrict__ fout) {
    constexpr int NT = H / 16;
    __shared__ f16 Ms[128][128];  // 32 KB
    const int tid = threadIdx.x;
    const int wave = tid >> 6, lane = tid & 63;
    const int l15 = lane & 15, quad = lane >> 4;
    const int m0 = blockIdx.x * 128;
    const int seg_i = tid & 127;            // segment within tile (2 threads/segment)
    int node = m0 + seg_i;
    node = node < NNODES ? node : NNODES - 1;

    float4v acc[2][NT];
#pragma unroll
    for (int i = 0; i < 2; ++i)
#pragma unroll
        for (int j = 0; j < NT; ++j) acc[i][j] = (float4v){0.f, 0.f, 0.f, 0.f};

    for (int r = 0; r < 8; ++r) {
        __syncthreads();  // previous slot's MFMA reads done
        // ---- build Ms: 2 passes, thread handles (segment, 32-dim part) ----
        int s = node * NREL + r;
        int truelen = cnt[s];
        int len = truelen < CAP ? truelen : CAP;
        float inv = truelen > 1 ? 1.f / (float)truelen : 1.f;
        const int4* bq = (const int4*)esrc + (size_t)s * CAPQ;
#pragma unroll
        for (int pass = 0; pass < 2; ++pass) {
            int part = ((tid >> 7) + pass * 2) * 32;  // 0/32 or 64/96
            float c[32];
#pragma unroll
            for (int t = 0; t < 32; ++t) c[t] = 0.f;
            for (int j4 = 0; j4 < (len + 3) >> 2; ++j4) {
                int4 q = bq[j4];
                int base = j4 * 4;
                int ids[4] = {q.x, q.y, q.z, q.w};
#pragma unroll
                for (int t = 0; t < 4; ++t) {
                    if (base + t < len) {
                        const half8* rp = (const half8*)(act + (size_t)ids[t] * 128 + part);
                        half8 v0 = rp[0], v1 = rp[1], v2 = rp[2], v3 = rp[3];
#pragma unroll
                        for (int u = 0; u < 8; ++u) {
                            c[u] += (float)v0[u];
                            c[8 + u] += (float)v1[u];
                            c[16 + u] += (float)v2[u];
                            c[24 + u] += (float)v3[u];
                        }
                    }
                }
            }
            int g0 = part >> 3;
#pragma unroll
            for (int gg = 0; gg < 4; ++gg) {
                half8 o;
#pragma unroll
                for (int t = 0; t < 8; ++t) o[t] = (f16)(c[gg * 8 + t] * inv);
                *(half8*)&Ms[seg_i][((g0 + gg) ^ (seg_i & 7)) * 8] = o;
            }
        }
        __syncthreads();
        // ---- MFMA over this K=128 slot; B fragments straight from global Bt ----
#pragma unroll
        for (int ks = 0; ks < 4; ++ks) {
            int gi = ks * 4 + quad;
            half8 af[2], bf[NT];
#pragma unroll
            for (int mt = 0; mt < 2; ++mt) {
                int row = wave * 32 + mt * 16 + l15;
                af[mt] = *(const half8*)&Ms[row][(gi ^ (row & 7)) * 8];
            }
#pragma unroll
            for (int nt = 0; nt < NT; ++nt)
                bf[nt] = *(const half8*)(Bt + (size_t)(nt * 16 + l15) * KDIM + r * 128 + gi * 8);
#pragma unroll
            for (int mt = 0; mt < 2; ++mt)
#pragma unroll
                for (int nt = 0; nt < NT; ++nt)
                    acc[mt][nt] = __builtin_amdgcn_mfma_f32_16x16x32_f16(
                        af[mt], bf[nt], acc[mt][nt], 0, 0, 0);
        }
    }

    // ---- root slot (r=8): A fragments direct from act, no LDS, no barrier ----
#pragma unroll
    for (int ks = 0; ks < 4; ++ks) {
        int gi = ks * 4 + quad;
        half8 af[2], bf[NT];
#pragma unroll
        for (int mt = 0; mt < 2; ++mt) {
            int row = m0 + wave * 32 + mt * 16 + l15;
            row = row < NNODES ? row : NNODES - 1;  // stores guarded; avoid OOB read
            af[mt] = *(const half8*)(act + (size_t)row * 128 + gi * 8);
        }
#pragma unroll
        for (int nt = 0; nt < NT; ++nt)
            bf[nt] = *(const half8*)(Bt + (size_t)(nt * 16 + l15) * KDIM + 1024 + gi * 8);
#pragma unroll
        for (int mt = 0; mt < 2; ++mt)
#pragma unroll
            for (int nt = 0; nt < NT; ++nt)
                acc[mt][nt] = __builtin_amdgcn_mfma_f32_16x16x32_f16(
                    af[mt], bf[nt], acc[mt][nt], 0, 0, 0);
    }

    // ---- epilogue ----
#pragma unroll
    for (int nt = 0; nt < NT; ++nt) {
        int col = nt * 16 + l15;
        float alpha, beta;
        if (MODE == 0) {
            float sc = g[col] * rsqrtf(rv[col] + 1e-5f);
            alpha = sc;
            beta = (bias[col] - rm[col]) * sc + be[col];
        } else {
            alpha = 1.f;
            beta = bias[col];
        }
#pragma unroll
        for (int mt = 0; mt < 2; ++mt)
#pragma unroll
            for (int rg = 0; rg < 4; ++rg) {
                int row = m0 + wave * 32 + mt * 16 + quad * 4 + rg;
                if (row < NNODES) {
                    float v = fmaf(acc[mt][nt][rg], alpha, beta);
                    if (MODE == 0) {
                        hout[(size_t)row * H + col] = (f16)fmaxf(v, 0.f);
                    } else {
                        fout[(size_t)row * H + col] = 1.f / (1.f + __expf(-v));
                    }
                }
            }
    }
}

extern "C" void kernel_launch(void* const* d_in, const int* in_sizes, int n_in,
                              void* d_out, int out_size, void* d_ws, size_t ws_size,
                              hipStream_t stream) {
    (void)in_sizes; (void)n_in; (void)out_size; (void)ws_size;
    const float* x   = (const float*)d_in[0];
    const int* ei    = (const int*)d_in[1];
    const int* et    = (const int*)d_in[2];
    const float* W1  = (const float*)d_in[3];
    const float* Wr1 = (const float*)d_in[4];
    const float* b1  = (const float*)d_in[5];
    const float* g1  = (const float*)d_in[6];
    const float* be1 = (const float*)d_in[7];
    const float* rm1 = (const float*)d_in[8];
    const float* rv1 = (const float*)d_in[9];
    const float* W2  = (const float*)d_in[10];
    const float* Wr2 = (const float*)d_in[11];
    const float* b2  = (const float*)d_in[12];
    const float* g2  = (const float*)d_in[13];
    const float* be2 = (const float*)d_in[14];
    const float* rm2 = (const float*)d_in[15];
    const float* rv2 = (const float*)d_in[16];
    const float* W3  = (const float*)d_in[17];
    const float* Wr3 = (const float*)d_in[18];
    const float* b3  = (const float*)d_in[19];
    const int* src = ei;
    const int* dst = ei + NEDGES;
    float* out = (float*)d_out;

    char* ws = (char*)d_ws;
    size_t off = 0;
    auto alloc = [&](size_t bytes) -> void* {
        off = (off + 255) & ~(size_t)255;
        void* p = ws + off;
        off += bytes;
        return p;
    };
    int* cnt  = (int*)alloc((size_t)NRSEG * 4);             // 1.6 MB
    int* esrc = (int*)alloc((size_t)NRSEG * CAP * 4);       // 38.4 MB
    f16* x16  = (f16*)alloc((size_t)NNODES * 128 * 2);      // 12.8 MB
    f16* ha   = (f16*)alloc((size_t)NNODES * 128 * 2);
    f16* hb   = (f16*)alloc((size_t)NNODES * 128 * 2);
    f16* Bt   = (f16*)alloc((size_t)320 * KDIM * 2);        // 0.74 MB (L1|L2|L3)

    hipMemsetAsync(cnt, 0, (size_t)NRSEG * 4, stream);
    bucket_fill<<<(NEDGES + 255) / 256, 256, 0, stream>>>(src, dst, et, cnt, esrc);

    const int EL_BLOCKS = (NNODES * 64 + 255) / 256;
    const int MT = (NNODES + 127) / 128;  // 391
    cvt_x<<<EL_BLOCKS, 256, 0, stream>>>(x, x16);
    prep_w_all<<<(320 * KDIM + 255) / 256, 256, 0, stream>>>(W1, Wr1, W2, Wr2, W3, Wr3, Bt);

    fused_layer<128, 0><<<MT, 256, 0, stream>>>(x16, Bt, cnt, esrc,
                                                b1, g1, be1, rm1, rv1, ha, nullptr);
    fused_layer<128, 0><<<MT, 256, 0, stream>>>(ha, Bt + (size_t)128 * KDIM, cnt, esrc,
                                                b2, g2, be2, rm2, rv2, hb, nullptr);
    fused_layer<64, 1><<<MT, 256, 0, stream>>>(hb, Bt + (size_t)256 * KDIM, cnt, esrc,
                                               b3, nullptr, nullptr, nullptr, nullptr,
                                               nullptr, out);
}

// Round 6
// 691.842 us; speedup vs baseline: 1.0167x; 1.0167x over previous
//
#include <hip/hip_runtime.h>

typedef _Float16 f16;
typedef __attribute__((ext_vector_type(8))) _Float16 half8;
typedef __attribute__((ext_vector_type(2))) _Float16 half2v;
typedef __attribute__((ext_vector_type(4))) float float4v;

#define NNODES 50000
#define NEDGES 800000
#define NREL 8
#define NRSEG (NNODES * NREL)   // 400000 segments (dst, rel)
#define KDIM 1152               // (R+1)*128
#define CAP 16                  // bucket capacity: one 64B cacheline of indices
#define CAPQ (CAP / 4)

// one kernel builds the whole edge structure: count + bucket scatter
__global__ void bucket_fill(const int* __restrict__ src, const int* __restrict__ dst,
                            const int* __restrict__ et, int* __restrict__ cnt,
                            int* __restrict__ esrc) {
    int e = blockIdx.x * blockDim.x + threadIdx.x;
    if (e < NEDGES) {
        int s = dst[e] * NREL + et[e];
        int p = atomicAdd(&cnt[s], 1);
        if (p < CAP) esrc[s * CAP + p] = src[e];
    }
}

// fp32 [N,128] -> fp16 [N,128]
__global__ void cvt_x(const float* __restrict__ x, f16* __restrict__ x16) {
    int t = blockIdx.x * blockDim.x + threadIdx.x;
    if (t >= NNODES * 64) return;
    float2 v = ((const float2*)x)[t];
    half2v o = {(f16)v.x, (f16)v.y};
    ((half2v*)x16)[t] = o;
}

// all 3 layers' weights -> fp16 Bt[h][k]: rows 0..127 L1, 128..255 L2, 256..319 L3
__global__ void prep_w_all(const float* __restrict__ W1, const float* __restrict__ Wr1,
                           const float* __restrict__ W2, const float* __restrict__ Wr2,
                           const float* __restrict__ W3, const float* __restrict__ Wr3,
                           f16* __restrict__ Bt) {
    int idx = blockIdx.x * blockDim.x + threadIdx.x;
    if (idx >= 320 * KDIM) return;
    int hg = idx / KDIM, k = idx - hg * KDIM;
    const float *W, *Wr;
    int h, H;
    if (hg < 128)      { W = W1; Wr = Wr1; h = hg;       H = 128; }
    else if (hg < 256) { W = W2; Wr = Wr2; h = hg - 128; H = 128; }
    else               { W = W3; Wr = Wr3; h = hg - 256; H = 64;  }
    float v = (k < 1024) ? W[(size_t)k * H + h] : Wr[(size_t)(k - 1024) * H + h];
    Bt[idx] = (f16)v;
}

// Fused RGCN layer, M-tile = 64 nodes (grid 782 -> ~38% occupancy potential).
// Per r in 0..7: build 64x128 segment-mean tile in LDS (XOR-swizzled 16B granules),
// MFMA against L2-resident Bt. Root slot reads act directly (no LDS, no barrier).
// Thread t: segment = lane (t&63), dim-part = (wave + pass*4)*16 -> c[16] only (no spill).
// MODE 0: bias+BN+ReLU -> fp16.  MODE 1: bias+sigmoid -> fp32.
template <int H, int MODE>
__global__ __launch_bounds__(256, 4) void fused_layer(
    const f16* __restrict__ act, const f16* __restrict__ Bt,
    const int* __restrict__ cnt, const int* __restrict__ esrc,
    const float* __restrict__ bias, const float* __restrict__ g,
    const float* __restrict__ be, const float* __restrict__ rm,
    const float* __restrict__ rv, f16* __restrict__ hout, float* __restrict__ fout) {
    constexpr int NT = H / 16;
    __shared__ f16 Ms[64][128];  // 16 KB
    const int tid = threadIdx.x;
    const int wave = tid >> 6, lane = tid & 63;
    const int l15 = lane & 15, quad = lane >> 4;
    const int m0 = blockIdx.x * 64;
    int node = m0 + lane;
    node = node < NNODES ? node : NNODES - 1;

    float4v acc[NT];
#pragma unroll
    for (int j = 0; j < NT; ++j) acc[j] = (float4v){0.f, 0.f, 0.f, 0.f};

    for (int r = 0; r < 8; ++r) {
        __syncthreads();  // previous slot's MFMA reads done
        int s = node * NREL + r;
        int truelen = cnt[s];
        int len = truelen < CAP ? truelen : CAP;
        float inv = truelen > 1 ? 1.f / (float)truelen : 1.f;
        const int4* bq = (const int4*)esrc + (size_t)s * CAPQ;
#pragma unroll
        for (int pass = 0; pass < 2; ++pass) {
            int part = (wave + pass * 4) * 16;  // 16 dims per task
            float c[16];
#pragma unroll
            for (int t = 0; t < 16; ++t) c[t] = 0.f;
            for (int j4 = 0; j4 < (len + 3) >> 2; ++j4) {
                int4 q = bq[j4];
                int base = j4 * 4;
                int ids[4] = {q.x, q.y, q.z, q.w};
#pragma unroll
                for (int t = 0; t < 4; ++t) {
                    if (base + t < len) {
                        const half8* rp = (const half8*)(act + (size_t)ids[t] * 128 + part);
                        half8 v0 = rp[0], v1 = rp[1];
#pragma unroll
                        for (int u = 0; u < 8; ++u) {
                            c[u] += (float)v0[u];
                            c[8 + u] += (float)v1[u];
                        }
                    }
                }
            }
            int g0 = part >> 3;  // even granule index
            half8 o0, o1;
#pragma unroll
            for (int t = 0; t < 8; ++t) {
                o0[t] = (f16)(c[t] * inv);
                o1[t] = (f16)(c[8 + t] * inv);
            }
            *(half8*)&Ms[lane][(g0 ^ (lane & 7)) * 8] = o0;
            *(half8*)&Ms[lane][((g0 + 1) ^ (lane & 7)) * 8] = o1;
        }
        __syncthreads();
        // ---- MFMA over this K=128 slot; B fragments from global (L1/L2-resident) ----
#pragma unroll
        for (int ks = 0; ks < 4; ++ks) {
            int gi = ks * 4 + quad;
            int row = wave * 16 + l15;
            half8 af = *(const half8*)&Ms[row][(gi ^ (row & 7)) * 8];
            half8 bf[NT];
#pragma unroll
            for (int nt = 0; nt < NT; ++nt)
                bf[nt] = *(const half8*)(Bt + (size_t)(nt * 16 + l15) * KDIM + r * 128 + gi * 8);
#pragma unroll
            for (int nt = 0; nt < NT; ++nt)
                acc[nt] = __builtin_amdgcn_mfma_f32_16x16x32_f16(af, bf[nt], acc[nt], 0, 0, 0);
        }
    }

    // ---- root slot (r=8): A fragments direct from act, no LDS, no barrier ----
#pragma unroll
    for (int ks = 0; ks < 4; ++ks) {
        int gi = ks * 4 + quad;
        int row = m0 + wave * 16 + l15;
        row = row < NNODES ? row : NNODES - 1;  // stores guarded; avoid OOB read
        half8 af = *(const half8*)(act + (size_t)row * 128 + gi * 8);
        half8 bf[NT];
#pragma unroll
        for (int nt = 0; nt < NT; ++nt)
            bf[nt] = *(const half8*)(Bt + (size_t)(nt * 16 + l15) * KDIM + 1024 + gi * 8);
#pragma unroll
        for (int nt = 0; nt < NT; ++nt)
            acc[nt] = __builtin_amdgcn_mfma_f32_16x16x32_f16(af, bf[nt], acc[nt], 0, 0, 0);
    }

    // ---- epilogue ----
#pragma unroll
    for (int nt = 0; nt < NT; ++nt) {
        int col = nt * 16 + l15;
        float alpha, beta;
        if (MODE == 0) {
            float sc = g[col] * rsqrtf(rv[col] + 1e-5f);
            alpha = sc;
            beta = (bias[col] - rm[col]) * sc + be[col];
        } else {
            alpha = 1.f;
            beta = bias[col];
        }
#pragma unroll
        for (int rg = 0; rg < 4; ++rg) {
            int row = m0 + wave * 16 + quad * 4 + rg;
            if (row < NNODES) {
                float v = fmaf(acc[nt][rg], alpha, beta);
                if (MODE == 0) {
                    hout[(size_t)row * H + col] = (f16)fmaxf(v, 0.f);
                } else {
                    fout[(size_t)row * H + col] = 1.f / (1.f + __expf(-v));
                }
            }
        }
    }
}

extern "C" void kernel_launch(void* const* d_in, const int* in_sizes, int n_in,
                              void* d_out, int out_size, void* d_ws, size_t ws_size,
                              hipStream_t stream) {
    (void)in_sizes; (void)n_in; (void)out_size; (void)ws_size;
    const float* x   = (const float*)d_in[0];
    const int* ei    = (const int*)d_in[1];
    const int* et    = (const int*)d_in[2];
    const float* W1  = (const float*)d_in[3];
    const float* Wr1 = (const float*)d_in[4];
    const float* b1  = (const float*)d_in[5];
    const float* g1  = (const float*)d_in[6];
    const float* be1 = (const float*)d_in[7];
    const float* rm1 = (const float*)d_in[8];
    const float* rv1 = (const float*)d_in[9];
    const float* W2  = (const float*)d_in[10];
    const float* Wr2 = (const float*)d_in[11];
    const float* b2  = (const float*)d_in[12];
    const float* g2  = (const float*)d_in[13];
    const float* be2 = (const float*)d_in[14];
    const float* rm2 = (const float*)d_in[15];
    const float* rv2 = (const float*)d_in[16];
    const float* W3  = (const float*)d_in[17];
    const float* Wr3 = (const float*)d_in[18];
    const float* b3  = (const float*)d_in[19];
    const int* src = ei;
    const int* dst = ei + NEDGES;
    float* out = (float*)d_out;

    char* ws = (char*)d_ws;
    size_t off = 0;
    auto alloc = [&](size_t bytes) -> void* {
        off = (off + 255) & ~(size_t)255;
        void* p = ws + off;
        off += bytes;
        return p;
    };
    int* cnt  = (int*)alloc((size_t)NRSEG * 4);             // 1.6 MB
    int* esrc = (int*)alloc((size_t)NRSEG * CAP * 4);       // 25.6 MB
    f16* x16  = (f16*)alloc((size_t)NNODES * 128 * 2);      // 12.8 MB
    f16* ha   = (f16*)alloc((size_t)NNODES * 128 * 2);
    f16* hb   = (f16*)alloc((size_t)NNODES * 128 * 2);
    f16* Bt   = (f16*)alloc((size_t)320 * KDIM * 2);        // 0.74 MB (L1|L2|L3)

    hipMemsetAsync(cnt, 0, (size_t)NRSEG * 4, stream);
    bucket_fill<<<(NEDGES + 255) / 256, 256, 0, stream>>>(src, dst, et, cnt, esrc);

    const int EL_BLOCKS = (NNODES * 64 + 255) / 256;
    const int MT = (NNODES + 63) / 64;  // 782
    cvt_x<<<EL_BLOCKS, 256, 0, stream>>>(x, x16);
    prep_w_all<<<(320 * KDIM + 255) / 256, 256, 0, stream>>>(W1, Wr1, W2, Wr2, W3, Wr3, Bt);

    fused_layer<128, 0><<<MT, 256, 0, stream>>>(x16, Bt, cnt, esrc,
                                                b1, g1, be1, rm1, rv1, ha, nullptr);
    fused_layer<128, 0><<<MT, 256, 0, stream>>>(ha, Bt + (size_t)128 * KDIM, cnt, esrc,
                                                b2, g2, be2, rm2, rv2, hb, nullptr);
    fused_layer<64, 1><<<MT, 256, 0, stream>>>(hb, Bt + (size_t)256 * KDIM, cnt, esrc,
                                               b3, nullptr, nullptr, nullptr, nullptr,
                                               nullptr, out);
}

// Round 7
// 610.735 us; speedup vs baseline: 1.1517x; 1.1328x over previous
//
#include <hip/hip_runtime.h>

typedef _Float16 f16;
typedef __attribute__((ext_vector_type(8))) _Float16 half8;
typedef __attribute__((ext_vector_type(2))) _Float16 half2v;
typedef __attribute__((ext_vector_type(4))) float float4v;

#define NNODES 50000
#define NEDGES 800000
#define NREL 8
#define NRSEG (NNODES * NREL)   // 400000 segments (dst, rel)
#define KDIM 1152               // (R+1)*128
#define CAP 16                  // bucket capacity: one 64B cacheline of indices
#define CAPQ (CAP / 4)

// one kernel builds the whole edge structure: count + bucket scatter
__global__ void bucket_fill(const int* __restrict__ src, const int* __restrict__ dst,
                            const int* __restrict__ et, int* __restrict__ cnt,
                            int* __restrict__ esrc) {
    int e = blockIdx.x * blockDim.x + threadIdx.x;
    if (e < NEDGES) {
        int s = dst[e] * NREL + et[e];
        int p = atomicAdd(&cnt[s], 1);
        if (p < CAP) esrc[s * CAP + p] = src[e];
    }
}

// fp32 [N,128] -> fp16 [N,128]
__global__ void cvt_x(const float* __restrict__ x, f16* __restrict__ x16) {
    int t = blockIdx.x * blockDim.x + threadIdx.x;
    if (t >= NNODES * 64) return;
    float2 v = ((const float2*)x)[t];
    half2v o = {(f16)v.x, (f16)v.y};
    ((half2v*)x16)[t] = o;
}

// all 3 layers' weights -> fp16 Bt[h][k]: rows 0..127 L1, 128..255 L2, 256..319 L3
__global__ void prep_w_all(const float* __restrict__ W1, const float* __restrict__ Wr1,
                           const float* __restrict__ W2, const float* __restrict__ Wr2,
                           const float* __restrict__ W3, const float* __restrict__ Wr3,
                           f16* __restrict__ Bt) {
    int idx = blockIdx.x * blockDim.x + threadIdx.x;
    if (idx >= 320 * KDIM) return;
    int hg = idx / KDIM, k = idx - hg * KDIM;
    const float *W, *Wr;
    int h, H;
    if (hg < 128)      { W = W1; Wr = Wr1; h = hg;       H = 128; }
    else if (hg < 256) { W = W2; Wr = Wr2; h = hg - 128; H = 128; }
    else               { W = W3; Wr = Wr3; h = hg - 256; H = 64;  }
    float v = (k < 1024) ? W[(size_t)k * H + h] : Wr[(size_t)(k - 1024) * H + h];
    Bt[idx] = (f16)v;
}

// Fused RGCN layer. 512 threads (8 waves), M-tile = 64 nodes, grid 782.
// Gather: thread -> (segment = tid>>3, 16-dim part = tid&7); 8 lanes of a wave share a
// segment, so edge-row reads are 256B wave-coalesced. Double-buffered Ms + 1 barrier/slot;
// gather(r+1) issued before MFMA(r). cnt for all 8 relations prefetched via 2 int4.
// MFMA: wave w -> m-tile (w&3), n-tiles (w>>2)*NTW..+NTW. Root slot direct from act.
// MODE 0: bias+BN+ReLU -> fp16.  MODE 1: bias+sigmoid -> fp32.
template <int H, int MODE>
__global__ __launch_bounds__(512, 5) void fused_layer(
    const f16* __restrict__ act, const f16* __restrict__ Bt,
    const int* __restrict__ cnt, const int* __restrict__ esrc,
    const float* __restrict__ bias, const float* __restrict__ g,
    const float* __restrict__ be, const float* __restrict__ rm,
    const float* __restrict__ rv, f16* __restrict__ hout, float* __restrict__ fout) {
    constexpr int NTW = H / 32;      // n-tiles per wave: 4 (H=128) or 2 (H=64)
    __shared__ f16 Ms[2][64][128];   // 32 KB double-buffered mean tile
    const int tid = threadIdx.x;
    const int wave = tid >> 6, lane = tid & 63;
    const int l15 = lane & 15, quad = lane >> 4;
    const int m0 = blockIdx.x * 64;
    const int seg_i = tid >> 3, part8 = tid & 7;
    const int mt = wave & 3, ntb = (wave >> 2) * NTW;
    int node = m0 + seg_i;
    node = node < NNODES ? node : NNODES - 1;

    // prefetch per-relation counts for this node (32B contiguous)
    int4 cq0 = ((const int4*)cnt)[node * 2];
    int4 cq1 = ((const int4*)cnt)[node * 2 + 1];
    int cnts[8] = {cq0.x, cq0.y, cq0.z, cq0.w, cq1.x, cq1.y, cq1.z, cq1.w};

    float4v acc[NTW];
#pragma unroll
    for (int j = 0; j < NTW; ++j) acc[j] = (float4v){0.f, 0.f, 0.f, 0.f};

    auto gather = [&](int r, int truelen, f16(*Mb)[128]) {
        int s = node * NREL + r;
        int len = truelen < CAP ? truelen : CAP;
        float inv = truelen > 1 ? 1.f / (float)truelen : 1.f;
        const int4* bq = (const int4*)esrc + (size_t)s * CAPQ;
        float c[16];
#pragma unroll
        for (int t = 0; t < 16; ++t) c[t] = 0.f;
        for (int j4 = 0; j4 < (len + 3) >> 2; ++j4) {
            int4 q = bq[j4];
            int ids[4] = {q.x, q.y, q.z, q.w};
            int base = j4 * 4;
#pragma unroll
            for (int t = 0; t < 4; ++t) {
                if (base + t < len) {
                    const half8* rp = (const half8*)(act + (size_t)ids[t] * 128 + part8 * 16);
                    half8 v0 = rp[0], v1 = rp[1];
#pragma unroll
                    for (int u = 0; u < 8; ++u) {
                        c[u] += (float)v0[u];
                        c[8 + u] += (float)v1[u];
                    }
                }
            }
        }
        half8 o0, o1;
#pragma unroll
        for (int t = 0; t < 8; ++t) {
            o0[t] = (f16)(c[t] * inv);
            o1[t] = (f16)(c[8 + t] * inv);
        }
        int g0 = part8 * 2;
        *(half8*)&Mb[seg_i][(g0 ^ (seg_i & 7)) * 8] = o0;
        *(half8*)&Mb[seg_i][((g0 + 1) ^ (seg_i & 7)) * 8] = o1;
    };

    auto mfma_slot = [&](int r, const f16(*Mb)[128]) {
        const int row = mt * 16 + l15;
#pragma unroll
        for (int ks = 0; ks < 4; ++ks) {
            int gi = ks * 4 + quad;
            half8 af = *(const half8*)&Mb[row][(gi ^ (row & 7)) * 8];
#pragma unroll
            for (int j = 0; j < NTW; ++j) {
                half8 bf = *(const half8*)(Bt + (size_t)((ntb + j) * 16 + l15) * KDIM +
                                           r * 128 + gi * 8);
                acc[j] = __builtin_amdgcn_mfma_f32_16x16x32_f16(af, bf, acc[j], 0, 0, 0);
            }
        }
    };

    gather(0, cnts[0], Ms[0]);
#pragma unroll
    for (int r = 0; r < 8; ++r) {
        __syncthreads();  // Ms[r&1] gather done; Ms[(r+1)&1] MFMA reads done
        if (r < 7) gather(r + 1, cnts[r + 1], Ms[(r + 1) & 1]);
        mfma_slot(r, Ms[r & 1]);
    }

    // root slot: A fragments direct from act
    {
        int arow = m0 + mt * 16 + l15;
        arow = arow < NNODES ? arow : NNODES - 1;
#pragma unroll
        for (int ks = 0; ks < 4; ++ks) {
            int gi = ks * 4 + quad;
            half8 af = *(const half8*)(act + (size_t)arow * 128 + gi * 8);
#pragma unroll
            for (int j = 0; j < NTW; ++j) {
                half8 bf = *(const half8*)(Bt + (size_t)((ntb + j) * 16 + l15) * KDIM +
                                           1024 + gi * 8);
                acc[j] = __builtin_amdgcn_mfma_f32_16x16x32_f16(af, bf, acc[j], 0, 0, 0);
            }
        }
    }

    // epilogue
#pragma unroll
    for (int j = 0; j < NTW; ++j) {
        int col = (ntb + j) * 16 + l15;
        float alpha, beta;
        if (MODE == 0) {
            float sc = g[col] * rsqrtf(rv[col] + 1e-5f);
            alpha = sc;
            beta = (bias[col] - rm[col]) * sc + be[col];
        } else {
            alpha = 1.f;
            beta = bias[col];
        }
#pragma unroll
        for (int rg = 0; rg < 4; ++rg) {
            int row = m0 + mt * 16 + quad * 4 + rg;
            if (row < NNODES) {
                float v = fmaf(acc[j][rg], alpha, beta);
                if (MODE == 0) {
                    hout[(size_t)row * H + col] = (f16)fmaxf(v, 0.f);
                } else {
                    fout[(size_t)row * H + col] = 1.f / (1.f + __expf(-v));
                }
            }
        }
    }
}

extern "C" void kernel_launch(void* const* d_in, const int* in_sizes, int n_in,
                              void* d_out, int out_size, void* d_ws, size_t ws_size,
                              hipStream_t stream) {
    (void)in_sizes; (void)n_in; (void)out_size; (void)ws_size;
    const float* x   = (const float*)d_in[0];
    const int* ei    = (const int*)d_in[1];
    const int* et    = (const int*)d_in[2];
    const float* W1  = (const float*)d_in[3];
    const float* Wr1 = (const float*)d_in[4];
    const float* b1  = (const float*)d_in[5];
    const float* g1  = (const float*)d_in[6];
    const float* be1 = (const float*)d_in[7];
    const float* rm1 = (const float*)d_in[8];
    const float* rv1 = (const float*)d_in[9];
    const float* W2  = (const float*)d_in[10];
    const float* Wr2 = (const float*)d_in[11];
    const float* b2  = (const float*)d_in[12];
    const float* g2  = (const float*)d_in[13];
    const float* be2 = (const float*)d_in[14];
    const float* rm2 = (const float*)d_in[15];
    const float* rv2 = (const float*)d_in[16];
    const float* W3  = (const float*)d_in[17];
    const float* Wr3 = (const float*)d_in[18];
    const float* b3  = (const float*)d_in[19];
    const int* src = ei;
    const int* dst = ei + NEDGES;
    float* out = (float*)d_out;

    char* ws = (char*)d_ws;
    size_t off = 0;
    auto alloc = [&](size_t bytes) -> void* {
        off = (off + 255) & ~(size_t)255;
        void* p = ws + off;
        off += bytes;
        return p;
    };
    int* cnt  = (int*)alloc((size_t)NRSEG * 4);             // 1.6 MB
    int* esrc = (int*)alloc((size_t)NRSEG * CAP * 4);       // 25.6 MB
    f16* x16  = (f16*)alloc((size_t)NNODES * 128 * 2);      // 12.8 MB
    f16* ha   = (f16*)alloc((size_t)NNODES * 128 * 2);
    f16* hb   = (f16*)alloc((size_t)NNODES * 128 * 2);
    f16* Bt   = (f16*)alloc((size_t)320 * KDIM * 2);        // 0.74 MB (L1|L2|L3)

    hipMemsetAsync(cnt, 0, (size_t)NRSEG * 4, stream);
    bucket_fill<<<(NEDGES + 255) / 256, 256, 0, stream>>>(src, dst, et, cnt, esrc);

    const int EL_BLOCKS = (NNODES * 64 + 255) / 256;
    const int MT = (NNODES + 63) / 64;  // 782
    cvt_x<<<EL_BLOCKS, 256, 0, stream>>>(x, x16);
    prep_w_all<<<(320 * KDIM + 255) / 256, 256, 0, stream>>>(W1, Wr1, W2, Wr2, W3, Wr3, Bt);

    fused_layer<128, 0><<<MT, 512, 0, stream>>>(x16, Bt, cnt, esrc,
                                                b1, g1, be1, rm1, rv1, ha, nullptr);
    fused_layer<128, 0><<<MT, 512, 0, stream>>>(ha, Bt + (size_t)128 * KDIM, cnt, esrc,
                                                b2, g2, be2, rm2, rv2, hb, nullptr);
    fused_layer<64, 1><<<MT, 512, 0, stream>>>(hb, Bt + (size_t)256 * KDIM, cnt, esrc,
                                               b3, nullptr, nullptr, nullptr, nullptr,
                                               nullptr, out);
}

// Round 8
// 550.182 us; speedup vs baseline: 1.2785x; 1.1101x over previous
//
#include <hip/hip_runtime.h>

typedef _Float16 f16;
typedef __attribute__((ext_vector_type(8))) _Float16 half8;
typedef __attribute__((ext_vector_type(2))) _Float16 half2v;
typedef __attribute__((ext_vector_type(4))) float float4v;

#define NNODES 50000
#define NEDGES 800000
#define NREL 8
#define NRSEG (NNODES * NREL)   // 400000 segments (dst, rel)
#define KDIM 1152               // (R+1)*128
#define CAP 16                  // bucket capacity: one 64B cacheline of indices
#define CAPQ (CAP / 4)

// one kernel builds the whole edge structure: count + bucket scatter
__global__ void bucket_fill(const int* __restrict__ src, const int* __restrict__ dst,
                            const int* __restrict__ et, int* __restrict__ cnt,
                            int* __restrict__ esrc) {
    int e = blockIdx.x * blockDim.x + threadIdx.x;
    if (e < NEDGES) {
        int s = dst[e] * NREL + et[e];
        int p = atomicAdd(&cnt[s], 1);
        if (p < CAP) esrc[s * CAP + p] = src[e];
    }
}

// fp32 [N,128] -> fp16 [N,128]
__global__ void cvt_x(const float* __restrict__ x, f16* __restrict__ x16) {
    int t = blockIdx.x * blockDim.x + threadIdx.x;
    if (t >= NNODES * 64) return;
    float2 v = ((const float2*)x)[t];
    half2v o = {(f16)v.x, (f16)v.y};
    ((half2v*)x16)[t] = o;
}

// all 3 layers' weights -> fp16 Bt[h][k]: rows 0..127 L1, 128..255 L2, 256..319 L3
__global__ void prep_w_all(const float* __restrict__ W1, const float* __restrict__ Wr1,
                           const float* __restrict__ W2, const float* __restrict__ Wr2,
                           const float* __restrict__ W3, const float* __restrict__ Wr3,
                           f16* __restrict__ Bt) {
    int idx = blockIdx.x * blockDim.x + threadIdx.x;
    if (idx >= 320 * KDIM) return;
    int hg = idx / KDIM, k = idx - hg * KDIM;
    const float *W, *Wr;
    int h, H;
    if (hg < 128)      { W = W1; Wr = Wr1; h = hg;       H = 128; }
    else if (hg < 256) { W = W2; Wr = Wr2; h = hg - 128; H = 128; }
    else               { W = W3; Wr = Wr3; h = hg - 256; H = 64;  }
    float v = (k < 1024) ? W[(size_t)k * H + h] : Wr[(size_t)(k - 1024) * H + h];
    Bt[idx] = (f16)v;
}

// Fused RGCN layer, ONE WAVE per 16-node M-tile. No LDS, no barriers.
// Lane (l15, quad) gathers exactly the 32 dims (k = ks*32 + quad*8 + u) that form its
// own MFMA A-fragments -> gather accumulates in c[32] (fp32), converts to 4 half8
// A-frags in VGPRs, MFMAs against L1-resident Bt. 50000 = 3125*16: no bounds checks.
// MODE 0: bias+BN+ReLU -> fp16.  MODE 1: bias+sigmoid -> fp32.
template <int H, int MODE>
__global__ __launch_bounds__(64, 4) void fused_layer(
    const f16* __restrict__ act, const f16* __restrict__ Bt,
    const int* __restrict__ cnt, const int* __restrict__ esrc,
    const float* __restrict__ bias, const float* __restrict__ g,
    const float* __restrict__ be, const float* __restrict__ rm,
    const float* __restrict__ rv, f16* __restrict__ hout, float* __restrict__ fout) {
    constexpr int NT = H / 16;  // 8 (H=128) or 4 (H=64)
    const int lane = threadIdx.x;
    const int l15 = lane & 15, quad = lane >> 4;
    const int m0 = blockIdx.x * 16;
    const int node = m0 + l15;

    // per-relation counts for this node (two int4, broadcast across quads)
    int4 cq0 = ((const int4*)cnt)[node * 2];
    int4 cq1 = ((const int4*)cnt)[node * 2 + 1];
    int cnts[8] = {cq0.x, cq0.y, cq0.z, cq0.w, cq1.x, cq1.y, cq1.z, cq1.w};

    float4v acc[NT];
#pragma unroll
    for (int j = 0; j < NT; ++j) acc[j] = (float4v){0.f, 0.f, 0.f, 0.f};

#pragma unroll
    for (int r = 0; r < 8; ++r) {
        int truelen = cnts[r];
        int len = truelen < CAP ? truelen : CAP;
        float inv = truelen > 1 ? 1.f / (float)truelen : 1.f;
        const int4* bq = (const int4*)esrc + (size_t)(node * NREL + r) * CAPQ;
        float c[32];
#pragma unroll
        for (int t = 0; t < 32; ++t) c[t] = 0.f;
        for (int j4 = 0; j4 < (len + 3) >> 2; ++j4) {
            int4 q = bq[j4];
            int ids[4] = {q.x, q.y, q.z, q.w};
            int base = j4 * 4;
#pragma unroll
            for (int t = 0; t < 4; ++t) {
                if (base + t < len) {
                    // 4 half8 loads at 64B stride; quads 0..3 tile each 64B chunk
                    const half8* rp = (const half8*)(act + (size_t)ids[t] * 128 + quad * 8);
                    half8 v0 = rp[0], v1 = rp[4], v2 = rp[8], v3 = rp[12];
#pragma unroll
                    for (int u = 0; u < 8; ++u) {
                        c[u] += (float)v0[u];
                        c[8 + u] += (float)v1[u];
                        c[16 + u] += (float)v2[u];
                        c[24 + u] += (float)v3[u];
                    }
                }
            }
        }
        half8 af[4];
#pragma unroll
        for (int ks = 0; ks < 4; ++ks)
#pragma unroll
            for (int u = 0; u < 8; ++u) af[ks][u] = (f16)(c[ks * 8 + u] * inv);
#pragma unroll
        for (int ks = 0; ks < 4; ++ks) {
#pragma unroll
            for (int nt = 0; nt < NT; ++nt) {
                half8 bf = *(const half8*)(Bt + (size_t)(nt * 16 + l15) * KDIM +
                                           r * 128 + ks * 32 + quad * 8);
                acc[nt] = __builtin_amdgcn_mfma_f32_16x16x32_f16(af[ks], bf, acc[nt], 0, 0, 0);
            }
        }
    }

    // root slot: A fragments direct from act (lane's own node row)
#pragma unroll
    for (int ks = 0; ks < 4; ++ks) {
        half8 af = *(const half8*)(act + (size_t)node * 128 + ks * 32 + quad * 8);
#pragma unroll
        for (int nt = 0; nt < NT; ++nt) {
            half8 bf = *(const half8*)(Bt + (size_t)(nt * 16 + l15) * KDIM +
                                       1024 + ks * 32 + quad * 8);
            acc[nt] = __builtin_amdgcn_mfma_f32_16x16x32_f16(af, bf, acc[nt], 0, 0, 0);
        }
    }

    // epilogue: D[m = quad*4+rg][n = l15] per n-tile
#pragma unroll
    for (int nt = 0; nt < NT; ++nt) {
        int col = nt * 16 + l15;
        float alpha, beta;
        if (MODE == 0) {
            float sc = g[col] * rsqrtf(rv[col] + 1e-5f);
            alpha = sc;
            beta = (bias[col] - rm[col]) * sc + be[col];
        } else {
            alpha = 1.f;
            beta = bias[col];
        }
#pragma unroll
        for (int rg = 0; rg < 4; ++rg) {
            int row = m0 + quad * 4 + rg;
            float v = fmaf(acc[nt][rg], alpha, beta);
            if (MODE == 0) {
                hout[(size_t)row * H + col] = (f16)fmaxf(v, 0.f);
            } else {
                fout[(size_t)row * H + col] = 1.f / (1.f + __expf(-v));
            }
        }
    }
}

extern "C" void kernel_launch(void* const* d_in, const int* in_sizes, int n_in,
                              void* d_out, int out_size, void* d_ws, size_t ws_size,
                              hipStream_t stream) {
    (void)in_sizes; (void)n_in; (void)out_size; (void)ws_size;
    const float* x   = (const float*)d_in[0];
    const int* ei    = (const int*)d_in[1];
    const int* et    = (const int*)d_in[2];
    const float* W1  = (const float*)d_in[3];
    const float* Wr1 = (const float*)d_in[4];
    const float* b1  = (const float*)d_in[5];
    const float* g1  = (const float*)d_in[6];
    const float* be1 = (const float*)d_in[7];
    const float* rm1 = (const float*)d_in[8];
    const float* rv1 = (const float*)d_in[9];
    const float* W2  = (const float*)d_in[10];
    const float* Wr2 = (const float*)d_in[11];
    const float* b2  = (const float*)d_in[12];
    const float* g2  = (const float*)d_in[13];
    const float* be2 = (const float*)d_in[14];
    const float* rm2 = (const float*)d_in[15];
    const float* rv2 = (const float*)d_in[16];
    const float* W3  = (const float*)d_in[17];
    const float* Wr3 = (const float*)d_in[18];
    const float* b3  = (const float*)d_in[19];
    const int* src = ei;
    const int* dst = ei + NEDGES;
    float* out = (float*)d_out;

    char* ws = (char*)d_ws;
    size_t off = 0;
    auto alloc = [&](size_t bytes) -> void* {
        off = (off + 255) & ~(size_t)255;
        void* p = ws + off;
        off += bytes;
        return p;
    };
    int* cnt  = (int*)alloc((size_t)NRSEG * 4);             // 1.6 MB
    int* esrc = (int*)alloc((size_t)NRSEG * CAP * 4);       // 25.6 MB
    f16* x16  = (f16*)alloc((size_t)NNODES * 128 * 2);      // 12.8 MB
    f16* ha   = (f16*)alloc((size_t)NNODES * 128 * 2);
    f16* hb   = (f16*)alloc((size_t)NNODES * 128 * 2);
    f16* Bt   = (f16*)alloc((size_t)320 * KDIM * 2);        // 0.74 MB (L1|L2|L3)

    hipMemsetAsync(cnt, 0, (size_t)NRSEG * 4, stream);
    bucket_fill<<<(NEDGES + 255) / 256, 256, 0, stream>>>(src, dst, et, cnt, esrc);

    const int EL_BLOCKS = (NNODES * 64 + 255) / 256;
    const int MT = NNODES / 16;  // 3125 one-wave blocks
    cvt_x<<<EL_BLOCKS, 256, 0, stream>>>(x, x16);
    prep_w_all<<<(320 * KDIM + 255) / 256, 256, 0, stream>>>(W1, Wr1, W2, Wr2, W3, Wr3, Bt);

    fused_layer<128, 0><<<MT, 64, 0, stream>>>(x16, Bt, cnt, esrc,
                                               b1, g1, be1, rm1, rv1, ha, nullptr);
    fused_layer<128, 0><<<MT, 64, 0, stream>>>(ha, Bt + (size_t)128 * KDIM, cnt, esrc,
                                               b2, g2, be2, rm2, rv2, hb, nullptr);
    fused_layer<64, 1><<<MT, 64, 0, stream>>>(hb, Bt + (size_t)256 * KDIM, cnt, esrc,
                                              b3, nullptr, nullptr, nullptr, nullptr,
                                              nullptr, out);
}